// Round 5
// baseline (684.936 us; speedup 1.0000x reference)
//
#include <hip/hip_runtime.h>
#include <hip/hip_bf16.h>
#include <stdint.h>

// Problem constants (B=8, T=4096, D=1024, H=1024)
#define B_   8
#define T_   4096
#define D_   1024
#define H_   1024
#define M_   (B_ * T_)   // 32768 rows
#define NC_  64          // scan chunks
#define TC_  64          // steps per chunk

// SEMANTICS LOCKED (r13 PASS, absmax 0.5): np-ref accumulation = KC512
// two-panel FMA. fixup_kc512 + 1e-3 flag guard must not change.
// r14: truncation split + v_perm packing (VERBATIM here). BEST gemm: 515us.
// r15-r18 post-mortems: swizzle halves conflicts but is TLP-hidden (+2%);
//   bigger tiles lose either occupancy (1 blk/CU serial) or registers
//   (acc spill). The r14 gemm structure is the local optimum; its MFMA
//   work is fixed by the locked 3-pass split. STOP touching the K-loop.
// r19 (this round): attack the non-gemm 150us. Fuse scan_p1 into the gemm
//   epilogue: each wave's 64 rows = exactly one scan chunk, and c=sigma(-k)
//   is already computed there. Per-chunk (C,V) built by ordered affine
//   composition: in-order 4-row segments -> cross-lane shfl_xor(16/32)
//   ordered combine -> in-lane i-chain (associative; ulp-level association
//   drift only). Razor sites: fixup rewrites v AFTER gemm, so a tiny
//   scan_p1r kernel re-runs the exact serial p1 recurrence for flagged
//   chunk-columns only (stream-ordered after fixup; duplicate sites write
//   identical values -> benign).

typedef __attribute__((ext_vector_type(4))) float f32x4;
typedef __attribute__((ext_vector_type(8))) short bfr8;   // 8 x bf16 (4 VGPRs)
typedef _Float16 f16;
typedef __attribute__((ext_vector_type(2))) _Float16 f16x2;

__device__ __forceinline__ unsigned short f2bf(float f) {
  unsigned int u = __float_as_uint(f);
  u += 0x7fffu + ((u >> 16) & 1u);      // RNE
  return (unsigned short)(u >> 16);
}
__device__ __forceinline__ float bf2f(unsigned short h) {
  return __uint_as_float(((unsigned int)h) << 16);
}

__device__ __forceinline__ void gload16(const void* g, void* l) {
  __builtin_amdgcn_global_load_lds((const __attribute__((address_space(1))) void*)g,
                                   (__attribute__((address_space(3))) void*)l,
                                   16, 0, 0);
}

// g(x) = exp(log_g(x)): x+0.5 for x>=0, e^5*sigmoid(x) for x<0
__device__ __forceinline__ float g_of(float hv) {
  return (hv >= 0.f) ? (hv + 0.5f)
                     : 148.4131591025766f / (1.f + __expf(-hv));
}

// ---- transpose + split W into Wt[n][k] hi/lo; fp32 Wh^T; zero fcnt ------
__global__ void prep_w(const float* __restrict__ Wz, const float* __restrict__ Wh,
                       unsigned short* __restrict__ wth, unsigned short* __restrict__ wtl,
                       float* __restrict__ whT, unsigned int* __restrict__ fcnt)
{
  if (blockIdx.x == 0 && blockIdx.y == 0 && threadIdx.x == 0) *fcnt = 0u;
  __shared__ float tile[32][33];
  int k0 = blockIdx.x * 32, n0 = blockIdx.y * 32;
  int tx = threadIdx.x & 31, ty = threadIdx.x >> 5;   // ty in 0..7
  bool ish = (n0 >= 1024);
  const float* src = ish ? Wh : Wz;
  int nn0 = ish ? (n0 - 1024) : n0;
#pragma unroll
  for (int i = 0; i < 4; i++) {
    int k = k0 + ty * 4 + i;
    tile[ty * 4 + i][tx] = src[(size_t)k * 1024 + nn0 + tx];   // coalesced in n
  }
  __syncthreads();
#pragma unroll
  for (int i = 0; i < 4; i++) {
    int n = n0 + ty * 4 + i;
    float v = tile[tx][ty * 4 + i];                   // = W[k0+tx][n]
    unsigned short hi = f2bf(v);                      // RNE here (one-time)
    unsigned short lo = f2bf(v - bf2f(hi));
    wth[(size_t)n * 1024 + k0 + tx] = hi;             // coalesced in k
    wtl[(size_t)n * 1024 + k0 + tx] = lo;
    if (ish)                                          // fp32 Wh^T for fixup
      whT[(size_t)(n - 1024) * 1024 + k0 + tx] = v;
  }
}

// ---------------- dual-B split-bf16 GEMM -> fused (k, v, scan-C/V) -------
__global__ __launch_bounds__(256, 2) void gemm_cv(
    const float* __restrict__ x,
    const unsigned short* __restrict__ wth, const unsigned short* __restrict__ wtl,
    const float* __restrict__ bz, const float* __restrict__ bhb,
    f16x2* __restrict__ cvbuf,
    unsigned int* __restrict__ fcnt, unsigned int* __restrict__ flist,
    unsigned int fcap,
    float* __restrict__ Cc, float* __restrict__ Vv)
{
  __shared__ __align__(16) unsigned short As_h[4096], As_l[4096];   // [128][32]
  __shared__ __align__(16) unsigned short Bzh[2048], Bzl[2048];     // [64][32]
  __shared__ __align__(16) unsigned short Bhh[2048], Bhl[2048];
  int tid = threadIdx.x;
  int lane = tid & 63, wv = tid >> 6;
  int wr = wv >> 1, wc = wv & 1;
  int lrow = lane & 15, lhalf = lane >> 4;

  // XCD swizzle (4096 % 8 == 0, bijective)
  int bid = blockIdx.x;
  int cpx = gridDim.x >> 3;
  int swz = (bid & 7) * cpx + (bid >> 3);
  int grp = swz >> 7, wi = swz & 127;
  int mt = grp * 8 + (wi & 7);      // 0..255
  int nt = wi >> 3;                 // 0..15
  int m0 = mt * 128, n0 = nt * 64;

  f32x4 accz[4][2], acch[4][2];
#pragma unroll
  for (int i = 0; i < 4; i++)
#pragma unroll
    for (int j = 0; j < 2; j++) {
      accz[i][j] = (f32x4){0.f, 0.f, 0.f, 0.f};
      acch[i][j] = (f32x4){0.f, 0.f, 0.f, 0.f};
    }

  int art = tid >> 3, ac4 = (tid & 7) * 4;
  int srow = tid >> 2, skb = (tid & 3) * 8;
  int blds = wv * 512;              // ushort units, wave-uniform

  for (int k0 = 0; k0 < D_; k0 += 32) {
    // ---- stage A: fp32 -> hi(trunc)/lo(trunc-of-residual) bf16 ----
#pragma unroll
    for (int p = 0; p < 4; p++) {
      int row = p * 32 + art;
      uint4 vu = *(const uint4*)&x[(size_t)(m0 + row) * D_ + k0 + ac4];
      unsigned int hi01 = __builtin_amdgcn_perm(vu.y, vu.x, 0x07060302u);
      unsigned int hi23 = __builtin_amdgcn_perm(vu.w, vu.z, 0x07060302u);
      float l0 = __uint_as_float(vu.x) - __uint_as_float(vu.x & 0xffff0000u);
      float l1 = __uint_as_float(vu.y) - __uint_as_float(vu.y & 0xffff0000u);
      float l2 = __uint_as_float(vu.z) - __uint_as_float(vu.z & 0xffff0000u);
      float l3 = __uint_as_float(vu.w) - __uint_as_float(vu.w & 0xffff0000u);
      unsigned int lo01 = __builtin_amdgcn_perm(__float_as_uint(l1),
                                                __float_as_uint(l0), 0x07060302u);
      unsigned int lo23 = __builtin_amdgcn_perm(__float_as_uint(l3),
                                                __float_as_uint(l2), 0x07060302u);
      *(uint2*)&As_h[row * 32 + ac4] = make_uint2(hi01, hi23);
      *(uint2*)&As_l[row * 32 + ac4] = make_uint2(lo01, lo23);
    }
    // ---- stage B tiles (both matrices, hi+lo) via global_load_lds ----
    {
      size_t gz = (size_t)(n0 + srow) * D_ + k0 + skb;          // Wz cols
      size_t gh = (size_t)(1024 + n0 + srow) * D_ + k0 + skb;   // Wh cols
      gload16(wth + gz, &Bzh[blds]);
      gload16(wtl + gz, &Bzl[blds]);
      gload16(wth + gh, &Bhh[blds]);
      gload16(wtl + gh, &Bhl[blds]);
    }
    __syncthreads();

    bfr8 ah[4], al[4], bzh[2], bzl[2], bhh[2], bhl[2];
    int ab = (wr * 64 + lrow) * 32 + lhalf * 8;
    int bb = (wc * 32 + lrow) * 32 + lhalf * 8;
#pragma unroll
    for (int f = 0; f < 4; f++) {
      ah[f] = *(const bfr8*)&As_h[ab + f * 512];
      al[f] = *(const bfr8*)&As_l[ab + f * 512];
    }
#pragma unroll
    for (int j = 0; j < 2; j++) {
      bzh[j] = *(const bfr8*)&Bzh[bb + j * 512];
      bzl[j] = *(const bfr8*)&Bzl[bb + j * 512];
      bhh[j] = *(const bfr8*)&Bhh[bb + j * 512];
      bhl[j] = *(const bfr8*)&Bhl[bb + j * 512];
    }
#pragma unroll
    for (int i = 0; i < 4; i++)
#pragma unroll
      for (int j = 0; j < 2; j++) {
        accz[i][j] = __builtin_amdgcn_mfma_f32_16x16x32_bf16(ah[i], bzh[j], accz[i][j], 0, 0, 0);
        accz[i][j] = __builtin_amdgcn_mfma_f32_16x16x32_bf16(al[i], bzh[j], accz[i][j], 0, 0, 0);
        accz[i][j] = __builtin_amdgcn_mfma_f32_16x16x32_bf16(ah[i], bzl[j], accz[i][j], 0, 0, 0);
        acch[i][j] = __builtin_amdgcn_mfma_f32_16x16x32_bf16(ah[i], bhh[j], acch[i][j], 0, 0, 0);
        acch[i][j] = __builtin_amdgcn_mfma_f32_16x16x32_bf16(al[i], bhh[j], acch[i][j], 0, 0, 0);
        acch[i][j] = __builtin_amdgcn_mfma_f32_16x16x32_bf16(ah[i], bhl[j], acch[i][j], 0, 0, 0);
      }
    __syncthreads();
  }

  // ---- fused epilogue: store k (f16), v = z*g(ht), flag razor sites, ----
  // ---- and compose per-chunk scan (C, V) — this wave's 64 rows = 1 chunk.
  // Ordered affine composition: apply (c,v) means V' = c*V + v.
  // op(a then b) = (Ca*Cb, fmaf(Cb, Va, Vb)).
#pragma unroll
  for (int j = 0; j < 2; j++) {
    int col = n0 + wc * 32 + j * 16 + lrow;
    float kb = bz[col], hb = bhb[col];
    float CC = 1.f, VV = 0.f;                       // chunk-so-far (rows < i*16)
#pragma unroll
    for (int i = 0; i < 4; i++) {
      int row0 = m0 + wr * 64 + i * 16 + lhalf * 4;
      float SC = 1.f, SV = 0.f;                     // this lane's 4-row segment
#pragma unroll
      for (int r = 0; r < 4; r++) {
        float kv = accz[i][j][r] + kb;
        float hv = acch[i][j][r] + hb;
        f16 kf = (f16)kv;
        float c  = 1.f / (1.f + __expf((float)kf));   // sigma(-k), from f16 k
        float v  = (1.f - c) * g_of(hv);              // z * g
        size_t off = (size_t)(row0 + r) * H_ + col;
        f16x2 pr; pr[0] = kf; pr[1] = (f16)v;
        cvbuf[off] = pr;
        float vr = (float)pr[1];                  // f16-rounded v, as p1 reads
        SV = fmaf(c, SV, vr);                     // in-order within segment
        SC *= c;
        if (__builtin_fabsf(hv) < 1e-3f) {        // log_g discontinuity guard
          unsigned int p = atomicAdd(fcnt, 1u);
          if (p < fcap) flist[p] = (unsigned int)off;
        }
      }
      // ordered cross-lane combine over lhalf (rows i*16 + 4*lhalf):
      // stage 1: lhalf pairs (0,1) and (2,3) via xor 16
      float oC = __shfl_xor(SC, 16);
      float oV = __shfl_xor(SV, 16);
      float nC = SC * oC;
      float nV = (lane & 16) ? fmaf(SC, oV, SV)    // partner first, mine second
                             : fmaf(oC, SV, oV);   // mine first, partner second
      // stage 2: combine (01) with (23) via xor 32
      oC = __shfl_xor(nC, 32);
      oV = __shfl_xor(nV, 32);
      float gC = nC * oC;
      float gV = (lane & 32) ? fmaf(nC, oV, nV)
                             : fmaf(oC, nV, oV);
      // append this 16-row group (rows ascending in i)
      VV = fmaf(gC, VV, gV);
      CC *= gC;
    }
    if (lane < 16) {                               // one writer per col
      int bb2 = m0 >> 12;                          // batch (T_ = 4096 rows)
      int ch  = ((m0 & 4095) >> 6) + wr;           // chunk within batch
      size_t oo = ((size_t)bb2 * NC_ + ch) * H_ + col;
      Cc[oo] = CC; Vv[oo] = VV;
    }
  }
}

// ---- replicate np-ref ordering at razor sites: KC512 two-panel FMA ------
// LOCKED (r12/r13): two in-order FMA half-chains, halves summed, then bias.
__global__ void fixup_kc512(const float* __restrict__ x, const float* __restrict__ whT,
                            const float* __restrict__ bhb, f16x2* cvbuf,
                            const unsigned int* __restrict__ fcnt,
                            const unsigned int* __restrict__ flist, unsigned int fcap)
{
  unsigned int n = *fcnt; if (n > fcap) n = fcap;
  unsigned int gtid = blockIdx.x * blockDim.x + threadIdx.x;
  unsigned int nt = gridDim.x * blockDim.x;
  const unsigned int lim = (unsigned int)M_ * (unsigned int)H_;
  for (unsigned int i = gtid; i < n; i += nt) {
    unsigned int o = flist[i];
    if (o >= lim) continue;                      // never scribble OOB
    unsigned int row = o >> 10, col = o & 1023u;
    const float* xr = x + (size_t)row * D_;
    const float* wr = whT + (size_t)col * D_;    // contiguous in d
    float a1 = 0.f, a2 = 0.f;
    for (int d = 0; d < 512; d++)                // panel 0: in-order FMA
      a1 = fmaf(xr[d], wr[d], a1);
    for (int d = 512; d < 1024; d++)             // panel 1: in-order FMA
      a2 = fmaf(xr[d], wr[d], a2);
    float hs = (a1 + a2) + bhb[col];             // halves, then bias
    float g  = (hs >= 0.f) ? (hs + 0.5f)
                           : 148.4131591025766f / (1.f + __expf(-hs));
    f16x2 pr = cvbuf[o];
    float z  = 1.f / (1.f + __expf(-(float)pr[0]));   // sigmoid(k)
    pr[1] = (f16)(z * g);
    cvbuf[o] = pr;
  }
}

// ---- razor repair for fused scan: redo exact serial p1 recurrence for ----
// ---- every flagged chunk-column (post-fixup v). Duplicates are benign. ---
__global__ void scan_p1r(const f16x2* __restrict__ cv,
                         const unsigned int* __restrict__ fcnt,
                         const unsigned int* __restrict__ flist, unsigned int fcap,
                         float* __restrict__ Cc, float* __restrict__ Vv)
{
  unsigned int n = *fcnt; if (n > fcap) n = fcap;
  unsigned int gtid = blockIdx.x * blockDim.x + threadIdx.x;
  unsigned int nt = gridDim.x * blockDim.x;
  const unsigned int lim = (unsigned int)M_ * (unsigned int)H_;
  for (unsigned int idx = gtid; idx < n; idx += nt) {
    unsigned int o = flist[idx];
    if (o >= lim) continue;
    unsigned int row = o >> 10, col = o & 1023u;
    unsigned int b  = row >> 12;                 // T_ = 4096
    unsigned int ch = (row & 4095u) >> 6;
    size_t base = ((size_t)b * T_ + (size_t)ch * TC_) * H_ + col;
    float C = 1.f, V = 0.f;
    for (int i = 0; i < TC_; i++) {              // exact p1 serial order
      f16x2 p = cv[base + (size_t)i * H_];
      float c = 1.f / (1.f + __expf((float)p[0]));
      V = fmaf(c, V, (float)p[1]);
      C *= c;
    }
    size_t oo = ((size_t)b * NC_ + ch) * H_ + col;
    Cc[oo] = C; Vv[oo] = V;
  }
}

// ---------------- scan phase 2: sequential chunk prefix -------------------
__global__ void scan_p2(const float* __restrict__ h0, const float* __restrict__ Cc,
                        const float* __restrict__ Vv, float* __restrict__ Hi)
{
  int idx = blockIdx.x * 256 + threadIdx.x;   // b*1024 + h, 8192 total
  float hs = g_of(h0[idx]);
  int b = idx >> 10, h = idx & 1023;
  for (int ch = 0; ch < NC_; ch++) {
    size_t o = ((size_t)b * NC_ + ch) * H_ + h;
    Hi[o] = hs;
    hs = fmaf(Cc[o], hs, Vv[o]);
  }
}

// ---------------- scan phase 3: stage chunk -> LDS, overwrite with h ------
__global__ void scan_p3(void* buf, const float* __restrict__ Hi)
{
  __shared__ f16x2 S[TC_][256];
  const f16x2* cv = (const f16x2*)buf;
  float* out = (float*)buf;
  int t = threadIdx.x;
  int hg = blockIdx.x, ch = blockIdx.y, b = blockIdx.z;
  int col = hg * 256 + t;
  size_t base = ((size_t)b * T_ + (size_t)ch * TC_) * H_ + col;
#pragma unroll 4
  for (int r = 0; r < TC_; r++)
    S[r][t] = cv[base + (size_t)r * H_];
  __syncthreads();
  float hs = Hi[((size_t)b * NC_ + ch) * H_ + col];
#pragma unroll 4
  for (int r = 0; r < TC_; r++) {
    f16x2 p = S[r][t];
    float c = 1.f / (1.f + __expf((float)p[0]));   // sigma(-k) in fp32
    hs = fmaf(c, hs, (float)p[1]);
    out[base + (size_t)r * H_] = hs;
  }
}

extern "C" void kernel_launch(void* const* d_in, const int* in_sizes, int n_in,
                              void* d_out, int out_size, void* d_ws, size_t ws_size,
                              hipStream_t stream)
{
  const float* x  = (const float*)d_in[0];
  const float* h0 = (const float*)d_in[1];
  const float* Wz = (const float*)d_in[2];
  const float* bz = (const float*)d_in[3];
  const float* Wh = (const float*)d_in[4];
  const float* bh = (const float*)d_in[5];
  char* ws = (char*)d_ws;

  // ws layout — total 20 MiB (robust to small ws_size)
  const size_t MiB = 1024u * 1024u;
  unsigned int* fcnt  = (unsigned int*)(ws);
  unsigned int* flist = (unsigned int*)(ws + 4096);
  const unsigned int fcap = 250u * 1024u;                  // <1 MiB list
  unsigned short* wth = (unsigned short*)(ws + 2 * MiB);   // 4 MiB [2048][1024]
  unsigned short* wtl = (unsigned short*)(ws + 6 * MiB);   // 4 MiB
  float* Cc = (float*)(ws + 10 * MiB);                     // 2 MiB
  float* Vv = (float*)(ws + 12 * MiB);                     // 2 MiB
  float* Hi = (float*)(ws + 14 * MiB);                     // 2 MiB
  float* whT = (float*)(ws + 16 * MiB);                    // 4 MiB [1024][1024]

  // d_out (exactly 128 MiB) holds interleaved (k,v) f16x2, overwritten by h.
  f16x2* cvbuf = (f16x2*)d_out;

  prep_w<<<dim3(32, 64), 256, 0, stream>>>(Wz, Wh, wth, wtl, whT, fcnt);
  gemm_cv<<<4096, 256, 0, stream>>>(x, wth, wtl, bz, bh, cvbuf, fcnt, flist, fcap, Cc, Vv);
  fixup_kc512<<<512, 256, 0, stream>>>(x, whT, bh, cvbuf, fcnt, flist, fcap);
  scan_p1r<<<256, 256, 0, stream>>>(cvbuf, fcnt, flist, fcap, Cc, Vv);
  scan_p2<<<32, 256, 0, stream>>>(h0, Cc, Vv, Hi);
  scan_p3<<<dim3(4, 64, 8), 256, 0, stream>>>(d_out, Hi);
}

// Round 6
// 672.523 us; speedup vs baseline: 1.0185x; 1.0185x over previous
//
#include <hip/hip_runtime.h>
#include <hip/hip_bf16.h>
#include <stdint.h>

// Problem constants (B=8, T=4096, D=1024, H=1024)
#define B_   8
#define T_   4096
#define D_   1024
#define H_   1024
#define M_   (B_ * T_)   // 32768 rows
#define NC_  64          // scan chunks
#define TC_  64          // steps per chunk

// SEMANTICS LOCKED (r13 PASS, absmax 0.5): np-ref accumulation = KC512
// two-panel FMA. fixup's KC512 chain + 1e-3 flag guard must not change.
// r14: truncation split + v_perm packing (VERBATIM). BEST gemm: 515us.
// r15-r18: K-loop micro-levers exhausted (swizzle TLP-hidden; bigger tiles
//   lose occupancy or spill). gemm structure LOCKED.
// r19: scan_p1 fused into gemm epilogue (ordered shfl tree) — PASSED, but
//   the scan_p1r razor-repair re-read flagged columns at 4KB stride
//   (~4-8KB fetched/site x ~25K sites + 64-deep serial chains) and cost
//   MORE than the streamed scan_p1 it replaced (685us total).
// r20 (this round): analytic repair, no re-read. V is affine in each v_t:
//   V = sum_t suffix(t)*v_t, suffix(t) = prod_{t'>t} c_t'; fixup changes
//   only v (c's untouched -> Cc needs no repair). Epilogue pass 2 computes
//   per-flagged-site suffix (in-lane residuals x 3-shfl lhalf-suffix x
//   group suffix) and pushes (off, suffix); fixup adds suffix*(v_new-v_old)
//   to Vv via one atomicAdd. scan_p1r DELETED.

typedef __attribute__((ext_vector_type(4))) float f32x4;
typedef __attribute__((ext_vector_type(8))) short bfr8;   // 8 x bf16 (4 VGPRs)
typedef _Float16 f16;
typedef __attribute__((ext_vector_type(2))) _Float16 f16x2;

__device__ __forceinline__ unsigned short f2bf(float f) {
  unsigned int u = __float_as_uint(f);
  u += 0x7fffu + ((u >> 16) & 1u);      // RNE
  return (unsigned short)(u >> 16);
}
__device__ __forceinline__ float bf2f(unsigned short h) {
  return __uint_as_float(((unsigned int)h) << 16);
}

__device__ __forceinline__ void gload16(const void* g, void* l) {
  __builtin_amdgcn_global_load_lds((const __attribute__((address_space(1))) void*)g,
                                   (__attribute__((address_space(3))) void*)l,
                                   16, 0, 0);
}

// g(x) = exp(log_g(x)): x+0.5 for x>=0, e^5*sigmoid(x) for x<0
__device__ __forceinline__ float g_of(float hv) {
  return (hv >= 0.f) ? (hv + 0.5f)
                     : 148.4131591025766f / (1.f + __expf(-hv));
}

// ---- transpose + split W into Wt[n][k] hi/lo; fp32 Wh^T; zero fcnt ------
__global__ void prep_w(const float* __restrict__ Wz, const float* __restrict__ Wh,
                       unsigned short* __restrict__ wth, unsigned short* __restrict__ wtl,
                       float* __restrict__ whT, unsigned int* __restrict__ fcnt)
{
  if (blockIdx.x == 0 && blockIdx.y == 0 && threadIdx.x == 0) *fcnt = 0u;
  __shared__ float tile[32][33];
  int k0 = blockIdx.x * 32, n0 = blockIdx.y * 32;
  int tx = threadIdx.x & 31, ty = threadIdx.x >> 5;   // ty in 0..7
  bool ish = (n0 >= 1024);
  const float* src = ish ? Wh : Wz;
  int nn0 = ish ? (n0 - 1024) : n0;
#pragma unroll
  for (int i = 0; i < 4; i++) {
    int k = k0 + ty * 4 + i;
    tile[ty * 4 + i][tx] = src[(size_t)k * 1024 + nn0 + tx];   // coalesced in n
  }
  __syncthreads();
#pragma unroll
  for (int i = 0; i < 4; i++) {
    int n = n0 + ty * 4 + i;
    float v = tile[tx][ty * 4 + i];                   // = W[k0+tx][n]
    unsigned short hi = f2bf(v);                      // RNE here (one-time)
    unsigned short lo = f2bf(v - bf2f(hi));
    wth[(size_t)n * 1024 + k0 + tx] = hi;             // coalesced in k
    wtl[(size_t)n * 1024 + k0 + tx] = lo;
    if (ish)                                          // fp32 Wh^T for fixup
      whT[(size_t)(n - 1024) * 1024 + k0 + tx] = v;
  }
}

// ---------------- dual-B split-bf16 GEMM -> fused (k, v, scan-C/V) -------
__global__ __launch_bounds__(256, 2) void gemm_cv(
    const float* __restrict__ x,
    const unsigned short* __restrict__ wth, const unsigned short* __restrict__ wtl,
    const float* __restrict__ bz, const float* __restrict__ bhb,
    f16x2* __restrict__ cvbuf,
    unsigned int* __restrict__ fcnt, unsigned int* __restrict__ flist,
    float* __restrict__ fsuf, unsigned int fcap,
    float* __restrict__ Cc, float* __restrict__ Vv)
{
  __shared__ __align__(16) unsigned short As_h[4096], As_l[4096];   // [128][32]
  __shared__ __align__(16) unsigned short Bzh[2048], Bzl[2048];     // [64][32]
  __shared__ __align__(16) unsigned short Bhh[2048], Bhl[2048];
  int tid = threadIdx.x;
  int lane = tid & 63, wv = tid >> 6;
  int wr = wv >> 1, wc = wv & 1;
  int lrow = lane & 15, lhalf = lane >> 4;

  // XCD swizzle (4096 % 8 == 0, bijective)
  int bid = blockIdx.x;
  int cpx = gridDim.x >> 3;
  int swz = (bid & 7) * cpx + (bid >> 3);
  int grp = swz >> 7, wi = swz & 127;
  int mt = grp * 8 + (wi & 7);      // 0..255
  int nt = wi >> 3;                 // 0..15
  int m0 = mt * 128, n0 = nt * 64;

  f32x4 accz[4][2], acch[4][2];
#pragma unroll
  for (int i = 0; i < 4; i++)
#pragma unroll
    for (int j = 0; j < 2; j++) {
      accz[i][j] = (f32x4){0.f, 0.f, 0.f, 0.f};
      acch[i][j] = (f32x4){0.f, 0.f, 0.f, 0.f};
    }

  int art = tid >> 3, ac4 = (tid & 7) * 4;
  int srow = tid >> 2, skb = (tid & 3) * 8;
  int blds = wv * 512;              // ushort units, wave-uniform

  for (int k0 = 0; k0 < D_; k0 += 32) {
    // ---- stage A: fp32 -> hi(trunc)/lo(trunc-of-residual) bf16 ----
#pragma unroll
    for (int p = 0; p < 4; p++) {
      int row = p * 32 + art;
      uint4 vu = *(const uint4*)&x[(size_t)(m0 + row) * D_ + k0 + ac4];
      unsigned int hi01 = __builtin_amdgcn_perm(vu.y, vu.x, 0x07060302u);
      unsigned int hi23 = __builtin_amdgcn_perm(vu.w, vu.z, 0x07060302u);
      float l0 = __uint_as_float(vu.x) - __uint_as_float(vu.x & 0xffff0000u);
      float l1 = __uint_as_float(vu.y) - __uint_as_float(vu.y & 0xffff0000u);
      float l2 = __uint_as_float(vu.z) - __uint_as_float(vu.z & 0xffff0000u);
      float l3 = __uint_as_float(vu.w) - __uint_as_float(vu.w & 0xffff0000u);
      unsigned int lo01 = __builtin_amdgcn_perm(__float_as_uint(l1),
                                                __float_as_uint(l0), 0x07060302u);
      unsigned int lo23 = __builtin_amdgcn_perm(__float_as_uint(l3),
                                                __float_as_uint(l2), 0x07060302u);
      *(uint2*)&As_h[row * 32 + ac4] = make_uint2(hi01, hi23);
      *(uint2*)&As_l[row * 32 + ac4] = make_uint2(lo01, lo23);
    }
    // ---- stage B tiles (both matrices, hi+lo) via global_load_lds ----
    {
      size_t gz = (size_t)(n0 + srow) * D_ + k0 + skb;          // Wz cols
      size_t gh = (size_t)(1024 + n0 + srow) * D_ + k0 + skb;   // Wh cols
      gload16(wth + gz, &Bzh[blds]);
      gload16(wtl + gz, &Bzl[blds]);
      gload16(wth + gh, &Bhh[blds]);
      gload16(wtl + gh, &Bhl[blds]);
    }
    __syncthreads();

    bfr8 ah[4], al[4], bzh[2], bzl[2], bhh[2], bhl[2];
    int ab = (wr * 64 + lrow) * 32 + lhalf * 8;
    int bb = (wc * 32 + lrow) * 32 + lhalf * 8;
#pragma unroll
    for (int f = 0; f < 4; f++) {
      ah[f] = *(const bfr8*)&As_h[ab + f * 512];
      al[f] = *(const bfr8*)&As_l[ab + f * 512];
    }
#pragma unroll
    for (int j = 0; j < 2; j++) {
      bzh[j] = *(const bfr8*)&Bzh[bb + j * 512];
      bzl[j] = *(const bfr8*)&Bzl[bb + j * 512];
      bhh[j] = *(const bfr8*)&Bhh[bb + j * 512];
      bhl[j] = *(const bfr8*)&Bhl[bb + j * 512];
    }
#pragma unroll
    for (int i = 0; i < 4; i++)
#pragma unroll
      for (int j = 0; j < 2; j++) {
        accz[i][j] = __builtin_amdgcn_mfma_f32_16x16x32_bf16(ah[i], bzh[j], accz[i][j], 0, 0, 0);
        accz[i][j] = __builtin_amdgcn_mfma_f32_16x16x32_bf16(al[i], bzh[j], accz[i][j], 0, 0, 0);
        accz[i][j] = __builtin_amdgcn_mfma_f32_16x16x32_bf16(ah[i], bzl[j], accz[i][j], 0, 0, 0);
        acch[i][j] = __builtin_amdgcn_mfma_f32_16x16x32_bf16(ah[i], bhh[j], acch[i][j], 0, 0, 0);
        acch[i][j] = __builtin_amdgcn_mfma_f32_16x16x32_bf16(al[i], bhh[j], acch[i][j], 0, 0, 0);
        acch[i][j] = __builtin_amdgcn_mfma_f32_16x16x32_bf16(ah[i], bhl[j], acch[i][j], 0, 0, 0);
      }
    __syncthreads();
  }

  // ---- fused epilogue: store (k,v); compose per-chunk (C,V); pass 2 ----
  // ---- flags razor sites with their scan-suffix for fixup's dV patch. ---
  // apply (c,v): V' = c*V + v ; op(a then b) = (Ca*Cb, fmaf(Cb, Va, Vb)).
#pragma unroll
  for (int j = 0; j < 2; j++) {
    int col = n0 + wc * 32 + j * 16 + lrow;
    float kb = bz[col], hb = bhb[col];
    float CC = 1.f, VV = 0.f;                       // chunk-so-far (rows < i*16)
    float SCs[4], gCs[4];
#pragma unroll
    for (int i = 0; i < 4; i++) {
      int row0 = m0 + wr * 64 + i * 16 + lhalf * 4;
      float SC = 1.f, SV = 0.f;                     // this lane's 4-row segment
#pragma unroll
      for (int r = 0; r < 4; r++) {
        float kv = accz[i][j][r] + kb;
        float hv = acch[i][j][r] + hb;
        f16 kf = (f16)kv;
        float c  = 1.f / (1.f + __expf((float)kf));   // sigma(-k), from f16 k
        float v  = (1.f - c) * g_of(hv);              // z * g
        size_t off = (size_t)(row0 + r) * H_ + col;
        f16x2 pr; pr[0] = kf; pr[1] = (f16)v;
        cvbuf[off] = pr;
        float vr = (float)pr[1];                  // f16-rounded v, as scan reads
        SV = fmaf(c, SV, vr);                     // in-order within segment
        SC *= c;
      }
      // ordered cross-lane combine over lhalf (rows i*16 + 4*lhalf):
      float oC = __shfl_xor(SC, 16);
      float oV = __shfl_xor(SV, 16);
      float nC = SC * oC;
      float nV = (lane & 16) ? fmaf(SC, oV, SV)    // partner earlier
                             : fmaf(oC, SV, oV);   // self earlier
      oC = __shfl_xor(nC, 32);
      oV = __shfl_xor(nV, 32);
      float gC = nC * oC;
      float gV = (lane & 32) ? fmaf(nC, oV, nV)
                             : fmaf(oC, nV, oV);
      VV = fmaf(gC, VV, gV);                       // append 16-row group
      CC *= gC;
      SCs[i] = SC; gCs[i] = gC;
    }
    if (lane < 16) {                               // one writer per col
      int bb2 = m0 >> 12;                          // batch (T_ = 4096 rows)
      int ch  = ((m0 & 4095) >> 6) + wr;           // chunk within batch
      size_t oo = ((size_t)bb2 * NC_ + ch) * H_ + col;
      Cc[oo] = CC; Vv[oo] = VV;
    }
    // ---- pass 2: razor flags + per-site suffix (prod of later c's) ----
    float gsuf3 = 1.f;
    float gsuf2 = gCs[3];
    float gsuf1 = gCs[2] * gCs[3];
    float gsuf0 = gCs[1] * gsuf1;
    float gsuf[4] = {gsuf0, gsuf1, gsuf2, gsuf3};
#pragma unroll
    for (int i = 0; i < 4; i++) {
      // lhalf-suffix: product of later lanes' segment products (same lrow)
      float a1 = __shfl(SCs[i], lrow + 16);
      float a2 = __shfl(SCs[i], lrow + 32);
      float a3 = __shfl(SCs[i], lrow + 48);
      float lh = 1.f;
      if (lhalf < 3) lh *= a3;
      if (lhalf < 2) lh *= a2;
      if (lhalf < 1) lh *= a1;
      float base = lh * gsuf[i];
      float cr[4], hv4[4];
#pragma unroll
      for (int r = 0; r < 4; r++) {
        float kv = accz[i][j][r] + kb;             // identical recompute
        f16 kf = (f16)kv;
        cr[r]  = 1.f / (1.f + __expf((float)kf));
        hv4[r] = acch[i][j][r] + hb;
      }
      float rs1 = cr[2] * cr[3];
      float rs[4] = {cr[1] * rs1, rs1, cr[3], 1.f};
      int row0 = m0 + wr * 64 + i * 16 + lhalf * 4;
#pragma unroll
      for (int r = 0; r < 4; r++) {
        if (__builtin_fabsf(hv4[r]) < 1e-3f) {     // log_g discontinuity guard
          unsigned int p = atomicAdd(fcnt, 1u);
          if (p < fcap) {
            flist[p] = (unsigned int)((size_t)(row0 + r) * H_ + col);
            fsuf[p]  = rs[r] * base;
          }
        }
      }
    }
  }
}

// ---- replicate np-ref ordering at razor sites: KC512 two-panel FMA ------
// LOCKED (r12/r13): two in-order FMA half-chains, halves summed, then bias.
// r20: additionally patches the fused scan's V by suffix*(v_new - v_old);
// C needs no repair (c's depend only on k, which fixup never changes).
__global__ void fixup_kc512(const float* __restrict__ x, const float* __restrict__ whT,
                            const float* __restrict__ bhb, f16x2* cvbuf,
                            const unsigned int* __restrict__ fcnt,
                            const unsigned int* __restrict__ flist,
                            const float* __restrict__ fsuf, unsigned int fcap,
                            float* __restrict__ Vv)
{
  unsigned int n = *fcnt; if (n > fcap) n = fcap;
  unsigned int gtid = blockIdx.x * blockDim.x + threadIdx.x;
  unsigned int nt = gridDim.x * blockDim.x;
  const unsigned int lim = (unsigned int)M_ * (unsigned int)H_;
  for (unsigned int i = gtid; i < n; i += nt) {
    unsigned int o = flist[i];
    if (o >= lim) continue;                      // never scribble OOB
    unsigned int row = o >> 10, col = o & 1023u;
    const float* xr = x + (size_t)row * D_;
    const float* wr = whT + (size_t)col * D_;    // contiguous in d
    float a1 = 0.f, a2 = 0.f;
    for (int d = 0; d < 512; d++)                // panel 0: in-order FMA
      a1 = fmaf(xr[d], wr[d], a1);
    for (int d = 512; d < 1024; d++)             // panel 1: in-order FMA
      a2 = fmaf(xr[d], wr[d], a2);
    float hs = (a1 + a2) + bhb[col];             // halves, then bias
    float g  = (hs >= 0.f) ? (hs + 0.5f)
                           : 148.4131591025766f / (1.f + __expf(-hs));
    f16x2 pr = cvbuf[o];
    float z  = 1.f / (1.f + __expf(-(float)pr[0]));   // sigmoid(k)
    float vold = (float)pr[1];
    pr[1] = (f16)(z * g);
    cvbuf[o] = pr;
    float dv = (float)pr[1] - vold;              // f16-rounded, as scan reads
    if (dv != 0.f) {
      unsigned int b = row >> 12, ch = (row >> 6) & 63u;
      atomicAdd(&Vv[((size_t)b * NC_ + ch) * H_ + col], fsuf[i] * dv);
    }
  }
}

// ---------------- scan phase 2: sequential chunk prefix -------------------
__global__ void scan_p2(const float* __restrict__ h0, const float* __restrict__ Cc,
                        const float* __restrict__ Vv, float* __restrict__ Hi)
{
  int idx = blockIdx.x * 256 + threadIdx.x;   // b*1024 + h, 8192 total
  float hs = g_of(h0[idx]);
  int b = idx >> 10, h = idx & 1023;
  for (int ch = 0; ch < NC_; ch++) {
    size_t o = ((size_t)b * NC_ + ch) * H_ + h;
    Hi[o] = hs;
    hs = fmaf(Cc[o], hs, Vv[o]);
  }
}

// ---------------- scan phase 3: stage chunk -> LDS, overwrite with h ------
__global__ void scan_p3(void* buf, const float* __restrict__ Hi)
{
  __shared__ f16x2 S[TC_][256];
  const f16x2* cv = (const f16x2*)buf;
  float* out = (float*)buf;
  int t = threadIdx.x;
  int hg = blockIdx.x, ch = blockIdx.y, b = blockIdx.z;
  int col = hg * 256 + t;
  size_t base = ((size_t)b * T_ + (size_t)ch * TC_) * H_ + col;
#pragma unroll 4
  for (int r = 0; r < TC_; r++)
    S[r][t] = cv[base + (size_t)r * H_];
  __syncthreads();
  float hs = Hi[((size_t)b * NC_ + ch) * H_ + col];
#pragma unroll 4
  for (int r = 0; r < TC_; r++) {
    f16x2 p = S[r][t];
    float c = 1.f / (1.f + __expf((float)p[0]));   // sigma(-k) in fp32
    hs = fmaf(c, hs, (float)p[1]);
    out[base + (size_t)r * H_] = hs;
  }
}

extern "C" void kernel_launch(void* const* d_in, const int* in_sizes, int n_in,
                              void* d_out, int out_size, void* d_ws, size_t ws_size,
                              hipStream_t stream)
{
  const float* x  = (const float*)d_in[0];
  const float* h0 = (const float*)d_in[1];
  const float* Wz = (const float*)d_in[2];
  const float* bz = (const float*)d_in[3];
  const float* Wh = (const float*)d_in[4];
  const float* bh = (const float*)d_in[5];
  char* ws = (char*)d_ws;

  // ws layout — total 20 MiB (robust to small ws_size)
  const size_t MiB = 1024u * 1024u;
  unsigned int* fcnt  = (unsigned int*)(ws);
  unsigned int* flist = (unsigned int*)(ws + 4096);        // 768 KiB
  float*        fsuf  = (float*)(ws + 1 * MiB);            // 768 KiB
  const unsigned int fcap = 192u * 1024u;
  unsigned short* wth = (unsigned short*)(ws + 2 * MiB);   // 4 MiB [2048][1024]
  unsigned short* wtl = (unsigned short*)(ws + 6 * MiB);   // 4 MiB
  float* Cc = (float*)(ws + 10 * MiB);                     // 2 MiB
  float* Vv = (float*)(ws + 12 * MiB);                     // 2 MiB
  float* Hi = (float*)(ws + 14 * MiB);                     // 2 MiB
  float* whT = (float*)(ws + 16 * MiB);                    // 4 MiB [1024][1024]

  // d_out (exactly 128 MiB) holds interleaved (k,v) f16x2, overwritten by h.
  f16x2* cvbuf = (f16x2*)d_out;

  prep_w<<<dim3(32, 64), 256, 0, stream>>>(Wz, Wh, wth, wtl, whT, fcnt);
  gemm_cv<<<4096, 256, 0, stream>>>(x, wth, wtl, bz, bh, cvbuf,
                                    fcnt, flist, fsuf, fcap, Cc, Vv);
  fixup_kc512<<<512, 256, 0, stream>>>(x, whT, bh, cvbuf,
                                       fcnt, flist, fsuf, fcap, Vv);
  scan_p2<<<32, 256, 0, stream>>>(h0, Cc, Vv, Hi);
  scan_p3<<<dim3(4, 64, 8), 256, 0, stream>>>(d_out, Hi);
}